// Round 1
// baseline (93.367 us; speedup 1.0000x reference)
//
#include <hip/hip_runtime.h>

#define N 8192
#define D 128
// (1/0.07) * log2(e): fold temperature AND base-2 conversion into A-side scale
#define SCALE_A 20.6098592f
#define NBX 64
#define NBY 8
#define NBLK (NBX * NBY)

using short8  = __attribute__((ext_vector_type(8))) short;
using float4v = __attribute__((ext_vector_type(4))) float;

#if __has_builtin(__builtin_amdgcn_exp2f)
#define EXP2(x) __builtin_amdgcn_exp2f(x)
#else
#define EXP2(x) __expf((x) * 0.69314718f)
#endif

// float -> bf16 (RNE) as raw ushort
static __device__ inline unsigned int f2bf(float f) {
    union { float f; unsigned int u; } x;
    x.f = f;
    unsigned int u = x.u;
    return (u + 0x7FFFu + ((u >> 16) & 1u)) >> 16;
}

// Pre-pass: emb fp32 -> bf16 (unscaled, B-side) and bf16*SCALE_A (A-side).
// Also zeroes tot/pos and the ticket. 65536 threads x 16 elements. (unchanged)
__global__ __launch_bounds__(256) void cl_prep(
    const float* __restrict__ emb, unsigned short* __restrict__ bfB,
    unsigned short* __restrict__ bfA, float* __restrict__ tot,
    int* __restrict__ ticket)
{
    const int t = blockIdx.x * 256 + threadIdx.x;
    const float* p = emb + (size_t)t * 16;
    uint4 ob[2], oa[2];
    #pragma unroll
    for (int h = 0; h < 2; ++h) {
        float4v f0 = *(const float4v*)(p + h * 8);
        float4v f1 = *(const float4v*)(p + h * 8 + 4);
        ob[h].x = f2bf(f0[0]) | (f2bf(f0[1]) << 16);
        ob[h].y = f2bf(f0[2]) | (f2bf(f0[3]) << 16);
        ob[h].z = f2bf(f1[0]) | (f2bf(f1[1]) << 16);
        ob[h].w = f2bf(f1[2]) | (f2bf(f1[3]) << 16);
        oa[h].x = f2bf(f0[0] * SCALE_A) | (f2bf(f0[1] * SCALE_A) << 16);
        oa[h].y = f2bf(f0[2] * SCALE_A) | (f2bf(f0[3] * SCALE_A) << 16);
        oa[h].z = f2bf(f1[0] * SCALE_A) | (f2bf(f1[1] * SCALE_A) << 16);
        oa[h].w = f2bf(f1[2] * SCALE_A) | (f2bf(f1[3] * SCALE_A) << 16);
    }
    ((uint4*)bfB)[t * 2]     = ob[0];
    ((uint4*)bfB)[t * 2 + 1] = ob[1];
    ((uint4*)bfA)[t * 2]     = oa[0];
    ((uint4*)bfA)[t * 2 + 1] = oa[1];
    if (t < 2 * N) tot[t] = 0.f;    // tot and pos are contiguous
    if (t == 0) *ticket = 0;
}

// DMA-stage one 128x128 bf16 tile: global_load_lds width=16, LINEAR lds dest,
// PRE-SWIZZLED global source (chunk ^ (row&15) is an involution, so the LDS
// image is byte-identical to the old ds_write path; read side unchanged).
// Per wave i-step: dest = wave-uniform base + lane*16 -> legal for the DMA.
static __device__ __forceinline__ void stage_tile(
    const uint4* __restrict__ bfB4, int cbase, uint4* lds_dst, int tid)
{
    const uint4* src = bfB4 + (size_t)cbase * 16;
    #pragma unroll
    for (int i = 0; i < 8; ++i) {
        const int g     = tid + i * 256;
        const int row   = g >> 4;
        const int chunk = g & 15;
        __builtin_amdgcn_global_load_lds(
            (const __attribute__((address_space(1))) void*)(src + row * 16 + (chunk ^ (row & 15))),
            (__attribute__((address_space(3))) void*)(lds_dst + g),
            16, 0, 0);
    }
}

// Each block: 128 rows x 1024 cols. Grid (64,8) = 512 blocks = exactly 2/CU.
// 2-phase pipeline (T3-minimum): double-buffered LDS tile, global_load_lds DMA,
// counted s_waitcnt vmcnt(8) (never 0 in the loop), raw s_barrier (no
// __syncthreads full-drain inside the loop — that drain was the old ~40us).
// Column labels live in LDS so the loop's vmem stream is ONLY the 8 DMA ops
// per iter and the vmcnt counting stays exact.
__global__ __launch_bounds__(256, 2) void cl_main(
    const unsigned short* __restrict__ bfA, const unsigned short* __restrict__ bfB,
    const int* __restrict__ labels,
    float* __restrict__ tot, float* __restrict__ pos,
    int* __restrict__ ticket, float* __restrict__ out)
{
    __shared__ uint4 ldsB[2][128 * 16];   // 2 x 32KB double buffer, swizzled image
    __shared__ int   s_collab[1024];      // labels for this block's 1024 columns
    __shared__ float sred[2][4];
    __shared__ int   s_ticket;

    const int tid  = threadIdx.x;
    const int lane = tid & 63;
    const int wave = tid >> 6;
    const int q    = lane >> 4;   // quad id 0..3
    const int c    = lane & 15;
    const int rw     = blockIdx.x * 128 + wave * 32;
    const int cbase0 = blockIdx.y * 1024;
    const uint4* bfB4 = (const uint4*)bfB;

    // kick off tile 0 DMA before doing any register preloads
    stage_tile(bfB4, cbase0, &ldsB[0][0], tid);

    // ---- A fragments: 16B loads from prescaled bf16 array, once per block ----
    short8 afrag[2][4];
    int rowlab[2][4];
    #pragma unroll
    for (int tr = 0; tr < 2; ++tr) {
        const int arow = rw + tr * 16 + c;
        #pragma unroll
        for (int ks = 0; ks < 4; ++ks)
            afrag[tr][ks] = *(const short8*)(bfA + (size_t)arow * D + ks * 32 + q * 8);
        #pragma unroll
        for (int reg = 0; reg < 4; ++reg)
            rowlab[tr][reg] = labels[rw + tr * 16 + q * 4 + reg];
    }

    // ---- column labels -> LDS once (keeps them out of the loop's vmcnt) ----
    {
        int4 lv = *(const int4*)(labels + cbase0 + tid * 4);
        *(int4*)(&s_collab[tid * 4]) = lv;
    }
    asm volatile("s_waitcnt lgkmcnt(0)" ::: "memory");  // s_collab writes done
    __builtin_amdgcn_s_barrier();

    float tot_a[2][4] = {{0.f,0.f,0.f,0.f},{0.f,0.f,0.f,0.f}};
    float pos_a[2][4] = {{0.f,0.f,0.f,0.f},{0.f,0.f,0.f,0.f}};

    int cur = 0;
    #pragma unroll 1
    for (int it = 0; it < 8; ++it) {
        // issue next tile's DMA, then wait for CURRENT tile only (8 newest in flight)
        if (it < 7) {
            stage_tile(bfB4, cbase0 + (it + 1) * 128, &ldsB[cur ^ 1][0], tid);
            asm volatile("s_waitcnt vmcnt(8)" ::: "memory");
        } else {
            asm volatile("s_waitcnt vmcnt(0)" ::: "memory");
        }
        __builtin_amdgcn_s_barrier();            // barrier A: tile[cur] visible
        __builtin_amdgcn_sched_barrier(0);       // no ds_read hoists above it

        int collab[8];
        #pragma unroll
        for (int tc = 0; tc < 8; ++tc) collab[tc] = s_collab[it * 128 + tc * 16 + c];

        // ---- MFMA: 2 tile-rows x 8 tile-cols, K=128 in 4 steps ----
        float4v acc[2][8];
        #pragma unroll
        for (int tr = 0; tr < 2; ++tr)
            #pragma unroll
            for (int tc = 0; tc < 8; ++tc) {
                float4v z = {0.f, 0.f, 0.f, 0.f};
                acc[tr][tc] = z;
            }

        const short8* ldsS = (const short8*)&ldsB[cur][0];
        #pragma unroll
        for (int ks = 0; ks < 4; ++ks) {
            // slot = (tc*16+c)*16 + ((ks*4+q)^c) -> base + tc*4096B immediates
            const short8* pk = ldsS + c * 16 + ((ks * 4 + q) ^ c);
            #pragma unroll
            for (int tc = 0; tc < 8; ++tc) {
                short8 b = pk[tc * 256];
                #pragma unroll
                for (int tr = 0; tr < 2; ++tr)
                    acc[tr][tc] = __builtin_amdgcn_mfma_f32_16x16x32_bf16(
                        afrag[tr][ks], b, acc[tr][tc], 0, 0, 0);
            }
        }

        // ---- epilogue: exp2, diagonal/label masking, per-row accumulate ----
        const int cbase = cbase0 + it * 128;
        #pragma unroll
        for (int tr = 0; tr < 2; ++tr) {
            const int rtile = rw + tr * 16;
            #pragma unroll
            for (int tc = 0; tc < 8; ++tc) {
                const bool diag_tile = (rtile == cbase + tc * 16);  // wave-uniform
                const int lc = collab[tc];
                #pragma unroll
                for (int reg = 0; reg < 4; ++reg) {
                    float v = EXP2(acc[tr][tc][reg]);
                    if (diag_tile && (q * 4 + reg) == c) v = 0.f;  // r == c
                    tot_a[tr][reg] += v;
                    if (rowlab[tr][reg] == lc) pos_a[tr][reg] += v;
                }
            }
        }

        __builtin_amdgcn_sched_barrier(0);       // no ds_read sinks below
        __builtin_amdgcn_s_barrier();            // barrier B: safe to overwrite
        cur ^= 1;
    }

    // ---- reduce over the 16 column-lanes, one atomic per row ----
    #pragma unroll
    for (int tr = 0; tr < 2; ++tr)
        #pragma unroll
        for (int reg = 0; reg < 4; ++reg) {
            float t = tot_a[tr][reg];
            float p = pos_a[tr][reg];
            #pragma unroll
            for (int m = 1; m < 16; m <<= 1) {
                t += __shfl_xor(t, m, 64);
                p += __shfl_xor(p, m, 64);
            }
            if (c == 0) {
                const int r = rw + tr * 16 + q * 4 + reg;
                atomicAdd(&tot[r], t);   // device-scope RMW at coherent point
                atomicAdd(&pos[r], p);
            }
        }

    // ---- last-block finalize: completion-wait + relaxed ticket (NO cache ops)
    asm volatile("s_waitcnt vmcnt(0)" ::: "memory");  // our atomics committed
    __syncthreads();
    if (tid == 0)
        s_ticket = __hip_atomic_fetch_add(ticket, 1, __ATOMIC_RELAXED,
                                          __HIP_MEMORY_SCOPE_AGENT);
    __syncthreads();
    if (s_ticket != NBLK - 1) return;

    float lsum = 0.f, lcnt = 0.f;
    #pragma unroll 4
    for (int i = tid; i < N; i += 256) {
        const float t = __hip_atomic_load(&tot[i], __ATOMIC_RELAXED,
                                          __HIP_MEMORY_SCOPE_AGENT);
        const float p = __hip_atomic_load(&pos[i], __ATOMIC_RELAXED,
                                          __HIP_MEMORY_SCOPE_AGENT);
        const float loss = -__logf(p / (t + 1e-8f) + 1e-8f);
        if (p > 0.f) { lsum += loss; lcnt += 1.f; }   // valid <=> pos>0
    }
    #pragma unroll
    for (int m = 1; m < 64; m <<= 1) {
        lsum += __shfl_xor(lsum, m, 64);
        lcnt += __shfl_xor(lcnt, m, 64);
    }
    if (lane == 0) { sred[0][wave] = lsum; sred[1][wave] = lcnt; }
    __syncthreads();
    if (tid == 0) {
        const float s = sred[0][0] + sred[0][1] + sred[0][2] + sred[0][3];
        const float n = sred[1][0] + sred[1][1] + sred[1][2] + sred[1][3];
        out[0] = (n > 0.f) ? s / fmaxf(n, 1.f) : 0.f;
    }
}

extern "C" void kernel_launch(void* const* d_in, const int* in_sizes, int n_in,
                              void* d_out, int out_size, void* d_ws, size_t ws_size,
                              hipStream_t stream) {
    const float* emb  = (const float*)d_in[0];
    const int* labels = (const int*)d_in[1];
    unsigned short* bfB = (unsigned short*)d_ws;                       // 2 MB
    unsigned short* bfA = bfB + (size_t)N * D;                         // 2 MB
    float* tot    = (float*)(bfA + (size_t)N * D);
    float* pos    = tot + N;
    int*   ticket = (int*)(pos + N);

    cl_prep<<<256, 256, 0, stream>>>(emb, bfB, bfA, tot, ticket);
    cl_main<<<dim3(NBX, NBY), 256, 0, stream>>>(bfA, bfB, labels, tot, pos,
                                                ticket, (float*)d_out);
}